// Round 14
// baseline (2390.680 us; speedup 1.0000x reference)
//
#include <hip/hip_runtime.h>

// SharedResidualQuantizer: 8-step residual VQ, N=32768 rows, K=8192 codes, d=64.
// Screen: f16 hi/scaled-lo MFMA, LDS-staged, 32 rows/wave, (256,3) — DO NOT raise
//   to (256,4): unified-RF allocator splits arch-VGPR to 64 and spills (r8,r10).
// srq_post (r14): ONE kernel, disjoint block roles: 1024 update blocks (parallel
//   shfl merge + streaming update + dn + bconv) and 128 refine blocks (re-derive
//   flags, fp64 rescan of rare ambiguous rows). Thin parallel work per block —
//   r11/r12 lesson: fat serial blocks latency-bind at 7% VALU.
//
// ws layout (bytes):
#define OFF_RES    0u          // resid f32 N*64                     (8 MB)
#define OFF_BH     8388608u    // Bh f16 8192*64 (per-depth)         (1 MB)
#define OFF_BL     9437184u    // Bl f16 (scaled 2^11)               (1 MB)
#define OFF_CSQD   10485760u   // csqD f64 8*8192                    (512 KB)
#define OFF_CSQH   11010048u   // csqH f32 8*8192 = -csq/2           (256 KB)
#define OFF_PM1    11403264u   // per-slice partials, N*8 each       (1 MB each)
#define OFF_PM2    12451840u   //   (pm1/pm2/pi1 double as dnpre scratch at startup)
#define OFF_PI1    13500416u
#define OFF_M0     14680064u   // M fp64 64x64, depth 0              (32 KB)
#define OFF_M7     14712832u   // M fp64 64x64, depth 7              (32 KB)
#define OFF_DNP    14745600u   // S1_0,S2_0,S1_7,S2_7 (512B each) + CS0,CS7 (16B each)
#define OFF_PCOM   14749760u   // per-block commit partials f64 8*1152 (72 KB)
#define OFF_PDN    15274048u   // per-block dn partials f64 2*1024   (16 KB)

#define TAU 3.0e-3f

typedef __attribute__((ext_vector_type(8))) _Float16 f16x8;
typedef __attribute__((ext_vector_type(4))) float f32x4;

__device__ __forceinline__ f32x4 mfma16(f16x8 a, f16x8 b, f32x4 c) {
  return __builtin_amdgcn_mfma_f32_16x16x32_f16(a, b, c, 0, 0, 0);
}

// ---------------- transpose x (B,C,H,W)->(N,64) into resid ----------------
__global__ __launch_bounds__(256) void srq_transpose_init(
    const float* __restrict__ x, float* __restrict__ resid)
{
  __shared__ float tile[64][65];
  const int b   = blockIdx.x >> 4;
  const int hw0 = (blockIdx.x & 15) << 6;
  const int t = threadIdx.x;
#pragma unroll
  for (int i = 0; i < 16; ++i) {
    int e = i * 256 + t;
    int c = e >> 6, hw = e & 63;
    tile[c][hw] = x[(size_t)b * 65536 + (size_t)c * 1024 + hw0 + hw];
  }
  __syncthreads();
#pragma unroll
  for (int i = 0; i < 16; ++i) {
    int e = i * 256 + t;
    int hw = e >> 6, c = e & 63;
    resid[((size_t)(b * 1024 + hw0 + hw) << 6) + c] = tile[c][hw];
  }
}

// ---------------- ||c||^2 (fp64) and -||c||^2/2 (f32) for all (depth,k) ----------------
__global__ __launch_bounds__(256) void srq_csq(
    const float* __restrict__ cb, double* __restrict__ csqD, float* __restrict__ csqH)
{
  int id = blockIdx.x * 256 + threadIdx.x;   // 65536
  const float* p = cb + ((size_t)id << 6);
  double s = 0.0;
#pragma unroll 8
  for (int d = 0; d < 64; ++d) { double v = (double)p[d]; s = fma(v, v, s); }
  csqD[id] = s;
  csqH[id] = (float)(-0.5 * s);
}

// ---------------- codebook -> f16 hi + scaled lo (depth 0 bootstrap) ----------------
__global__ __launch_bounds__(256) void srq_bconv(
    const float* __restrict__ cb, _Float16* __restrict__ Bh, _Float16* __restrict__ Bl)
{
  int id0 = (blockIdx.x * 256 + threadIdx.x) * 4;   // 512 blocks x 4/thread = 524288
  float4 v = *(const float4*)(cb + id0);
  const float f[4] = {v.x, v.y, v.z, v.w};
#pragma unroll
  for (int u = 0; u < 4; ++u) {
    _Float16 h = (_Float16)f[u];
    Bh[id0 + u] = h;
    Bl[id0 + u] = (_Float16)((f[u] - (float)h) * 2048.f);
  }
}

// ---- d_norm precompute stage 1: per-block fp64 partials of M=sum c c^T,
// ---- S1=sum c, S2=sum csq*c.  32 blocks x 256 k each. Deterministic. ----
__global__ __launch_bounds__(256) void srq_dnpre_partial(
    const float* __restrict__ cb, const double* __restrict__ csqD,
    double* __restrict__ Pm, double* __restrict__ Ps1, double* __restrict__ Ps2)
{
  __shared__ float ch[32][64];
  const int t = threadIdx.x;
  const int b = blockIdx.x;
  const int i = t >> 2;              // M row (constant per thread)
  const int j0 = (t & 3) << 4;       // M col base (16 cols per thread)
  double acc[16];
#pragma unroll
  for (int n = 0; n < 16; ++n) acc[n] = 0.0;
  double s1 = 0.0, s2 = 0.0;
  for (int c8 = 0; c8 < 8; ++c8) {
    const int kbase = b * 256 + c8 * 32;
    __syncthreads();
    const float* src = cb + (size_t)kbase * 64;
#pragma unroll
    for (int u = 0; u < 2; ++u)
      *(float4*)(&ch[0][0] + (u * 256 + t) * 4) = *(const float4*)(src + (u * 256 + t) * 4);
    __syncthreads();
#pragma unroll 4
    for (int kk = 0; kk < 32; ++kk) {
      double ci = (double)ch[kk][i];
#pragma unroll
      for (int n = 0; n < 16; ++n)
        acc[n] = fma(ci, (double)ch[kk][j0 + n], acc[n]);
    }
    if (t < 64) {
#pragma unroll 4
      for (int kk = 0; kk < 32; ++kk) {
        double v = (double)ch[kk][t];
        s1 += v;
        s2 = fma(csqD[kbase + kk], v, s2);
      }
    }
  }
  double* dst = Pm + ((size_t)b << 12) + (i << 6) + j0;
#pragma unroll
  for (int n = 0; n < 16; ++n) dst[n] = acc[n];
  if (t < 64) { Ps1[(b << 6) + t] = s1; Ps2[(b << 6) + t] = s2; }
}

// ---- d_norm precompute stage 2: reduce partials (fixed order) + CS ----
__global__ __launch_bounds__(256) void srq_dnpre_reduce(
    const double* __restrict__ Pm, const double* __restrict__ Ps1,
    const double* __restrict__ Ps2, const double* __restrict__ csqD,
    double* __restrict__ Mmat, double* __restrict__ S1, double* __restrict__ S2,
    double* __restrict__ CS)
{
  const int t = threadIdx.x;
  if (blockIdx.x < 16) {
    const int e = blockIdx.x * 256 + t;
    double a = 0.0;
    for (int b = 0; b < 32; ++b) a += Pm[((size_t)b << 12) + e];
    Mmat[e] = a;
  } else {
    __shared__ double red[256];
    if (t < 64) {
      double a1 = 0.0, a2 = 0.0;
      for (int b = 0; b < 32; ++b) { a1 += Ps1[(b << 6) + t]; a2 += Ps2[(b << 6) + t]; }
      S1[t] = a1; S2[t] = a2;
    }
    double c1 = 0.0, c2 = 0.0;
    for (int k = t; k < 8192; k += 256) { double q = csqD[k]; c1 += q; c2 = fma(q, q, c2); }
    red[t] = c1;
    __syncthreads();
    for (int o = 128; o; o >>= 1) { if (t < o) red[t] += red[t + o]; __syncthreads(); }
    if (t == 0) CS[0] = red[0];
    __syncthreads();
    red[t] = c2;
    __syncthreads();
    for (int o = 128; o; o >>= 1) { if (t < o) red[t] += red[t + o]; __syncthreads(); }
    if (t == 0) CS[1] = red[0];
  }
}

// ---------------- stage one 64-code tile (hi+lo, 16 KB) to LDS ----------------
__device__ __forceinline__ void stage_tile(
    const _Float16* __restrict__ Bh, const _Float16* __restrict__ Bl,
    char* ldsbase, int k0, int wid, int lane)
{
#pragma unroll
  for (int q = 0; q < 4; ++q) {
    int ub = (((q << 2) + wid) << 10);       // wave-uniform dest base (1 KB chunks)
    int db = ub + lane * 16;                 // effective dest byte (for src swizzle)
    int half = db >> 13;                     // 0 = hi tile, 1 = lo tile
    int rowh = (db & 8191) >> 7;             // code row within half
    int soff = (db & 127) ^ ((rowh & 7) << 4);  // inverse-swizzled source offset
    const _Float16* g = (half ? Bl : Bh) + (((size_t)(k0 + rowh)) << 6) + (soff >> 1);
    __builtin_amdgcn_global_load_lds(
        (const __attribute__((address_space(1))) void*)g,
        (__attribute__((address_space(3))) void*)(ldsbase + ub), 16, 0, 0);
  }
}

// ------- MFMA screen: 32 rows/wave, LDS-staged B, per-row top-2 over 1024 codes -------
// (256,3): compiler-chosen 84 VGPR, no split/spill. Measured: (256,4) spills (r8,r10).
__global__ __launch_bounds__(256, 3) void srq_screen_mfma(
    const _Float16* __restrict__ Bh, const _Float16* __restrict__ Bl,
    const float* __restrict__ csqH, const float* __restrict__ resid,
    float* __restrict__ pm1, float* __restrict__ pm2, int* __restrict__ pi1)
{
  __shared__ char lds[32768];                // 2 bufs x (Bh 8KB + Bl 8KB)
  const int tid = threadIdx.x;
  const int lane = tid & 63;
  const int wid = tid >> 6;
  const int rg = blockIdx.x & 255;           // row group (128 rows/block)
  const int ks = blockIdx.x >> 8;            // k slice (1024 codes)
  const int k0g = ks << 10;
  const int wrow0 = (rg << 7) + (wid << 5);  // wave owns 32 rows
  const int lr = lane & 15;
  const int kg = lane >> 4;

  // A fragments: 32 rows x 64 d, f16 hi + scaled lo, from exact f32 residual
  f16x8 ah[2][2], al[2][2];
#pragma unroll
  for (int rf = 0; rf < 2; ++rf)
#pragma unroll
    for (int s = 0; s < 2; ++s) {
      const float* rp = resid + (((size_t)(wrow0 + rf * 16 + lr)) << 6) + s * 32 + kg * 8;
      float4 v0 = *(const float4*)rp;
      float4 v1 = *(const float4*)(rp + 4);
      float f[8] = {v0.x, v0.y, v0.z, v0.w, v1.x, v1.y, v1.z, v1.w};
      f16x8 h, l;
#pragma unroll
      for (int e = 0; e < 8; ++e) {
        _Float16 hh = (_Float16)f[e];
        h[e] = hh;
        l[e] = (_Float16)((f[e] - (float)hh) * 2048.f);
      }
      ah[rf][s] = h;
      al[rf][s] = l;
    }

  // top-2 tracked in sigma-domain (sigma = -s/2; argmin s == argmax sigma)
  float m1[8], m2[8];
  int i1[8];
#pragma unroll
  for (int j = 0; j < 8; ++j) { m1[j] = -3e38f; m2[j] = -3e38f; i1[j] = 0; }

  stage_tile(Bh, Bl, lds, k0g, wid, lane);

  for (int t = 0; t < 16; ++t) {
    __syncthreads();   // compiler drains vmcnt here: staged tile t visible
    if (t < 15) stage_tile(Bh, Bl, lds + (((t + 1) & 1) << 14), k0g + ((t + 1) << 6), wid, lane);
    const char* bb = lds + ((t & 1) << 14);
    const int k0 = k0g + (t << 6);
#pragma unroll
    for (int cf = 0; cf < 4; ++cf) {
      const int cl = cf * 16 + lr;           // local code (B-frag col)
      const int sw = (cl & 7) << 4;          // XOR swizzle
      const int ro = cl * 128 + kg * 16;
      f16x8 bh0 = *(const f16x8*)(bb + ((ro) ^ sw));
      f16x8 bh1 = *(const f16x8*)(bb + ((ro + 64) ^ sw));
      f16x8 bl0 = *(const f16x8*)(bb + 8192 + ((ro) ^ sw));
      f16x8 bl1 = *(const f16x8*)(bb + 8192 + ((ro + 64) ^ sw));
      const int code = k0 + cl;
      const float ci = csqH[code];           // -csq/2, folded into acc init
#pragma unroll
      for (int rf = 0; rf < 2; ++rf) {
        f32x4 a1 = {ci, ci, ci, ci};         // hi*hi (exact products) - csq/2
        f32x4 a2 = {0.f, 0.f, 0.f, 0.f};     // cross terms at 2^11 scale
        a1 = mfma16(ah[rf][0], bh0, a1);
        a1 = mfma16(ah[rf][1], bh1, a1);
        a2 = mfma16(ah[rf][0], bl0, a2);
        a2 = mfma16(al[rf][0], bh0, a2);
        a2 = mfma16(ah[rf][1], bl1, a2);
        a2 = mfma16(al[rf][1], bh1, a2);
#pragma unroll
        for (int r = 0; r < 4; ++r) {
          // sigma = -s/2 = a1 + 2^-11*a2 ; bigger sigma == smaller dist
          float sg = fmaf(4.8828125e-4f, a2[r], a1[r]);
          const int j = rf * 4 + r;          // row = wrow0 + rf*16 + kg*4 + r
          bool gt = sg > m1[j];
          m2[j] = __builtin_amdgcn_fmed3f(sg, m1[j], m2[j]);
          m1[j] = fmaxf(m1[j], sg);
          i1[j] = gt ? code : i1[j];
        }
      }
    }
  }

  // merge across the 16 lanes (lane^{1,2,4,8}) sharing each row; max-domain
#pragma unroll
  for (int j = 0; j < 8; ++j) {
    float a1 = m1[j], a2 = m2[j];
    int ai = i1[j];
#pragma unroll
    for (int w = 1; w <= 8; w <<= 1) {
      float b1 = __shfl_xor(a1, w);
      float b2 = __shfl_xor(a2, w);
      int bi = __shfl_xor(ai, w);
      float nm2 = fmaxf(fminf(a1, b1), fmaxf(a2, b2));
      bool bet = (b1 > a1) || (b1 == a1 && bi < ai);
      a1 = fmaxf(a1, b1);
      ai = bet ? bi : ai;
      a2 = nm2;
    }
    if (lr == 0) {
      const int row = wrow0 + (j >> 2) * 16 + kg * 4 + (j & 3);
      pm1[row * 8 + ks] = -2.f * a1;         // back to s-domain
      pm2[row * 8 + ks] = -2.f * a2;
      pi1[row * 8 + ks] = ai;
    }
  }
}

// ------- fused post-screen: update blocks (0-1023) + refine blocks (1024-1151) -------
// Disjoint row ownership: update blocks handle unflagged rows; refine blocks
// re-derive flags for their 256-row range and handle flagged rows end-to-end.
// Fully deterministic: static Pcom slots, ballot-ordered lists, no global atomics.
template <int NEED_DN>
__global__ __launch_bounds__(256) void srq_post(
    const float* __restrict__ pm1, const float* __restrict__ pm2,
    const int* __restrict__ pi1, const float* __restrict__ cb,
    const double* __restrict__ csqD,
    float* __restrict__ resid, float* __restrict__ codesF,
    double* __restrict__ Pcom, double* __restrict__ Pdn,
    const double* __restrict__ Mmat, const double* __restrict__ S1v,
    const double* __restrict__ S2v, const double* __restrict__ CS,
    const float* __restrict__ cbNext, _Float16* __restrict__ BhN,
    _Float16* __restrict__ BlN, int dep)
{
  const int t = threadIdx.x;

  if (blockIdx.x < 1024) {
    // ---------------- update path ----------------
    __shared__ double w4[4];
    __shared__ double d4[4];
    const int b = blockIdx.x;
    const int team = t >> 6;
    const int c = t & 63;
    const int row0 = b * 32 + team * 8;

    // fused bconv for next depth: 1024 blocks x 256 threads x 2 = 524288 elems
    if (cbNext) {
      int gid = b * 512 + t;
#pragma unroll
      for (int u = 0; u < 2; ++u) {
        int g2 = gid + u * 256;
        float v = cbNext[g2];
        _Float16 h = (_Float16)v;
        BhN[g2] = h;
        BlN[g2] = (_Float16)((v - (float)h) * 2048.f);
      }
    }

    // parallel merge: lane c covers (row row0+(c>>3), slice c&7)
    const int mrow = row0 + (c >> 3);
    float a1 = pm1[mrow * 8 + (c & 7)];
    float a2 = pm2[mrow * 8 + (c & 7)];
    int ai = pi1[mrow * 8 + (c & 7)];
#pragma unroll
    for (int w = 1; w <= 4; w <<= 1) {
      float b1 = __shfl_xor(a1, w);
      float b2 = __shfl_xor(a2, w);
      int bi = __shfl_xor(ai, w);
      float nm2 = fminf(fmaxf(a1, b1), fminf(a2, b2));
      bool bet = (b1 < a1) || (b1 == a1 && bi < ai);
      a1 = fminf(a1, b1);
      ai = bet ? bi : ai;
      a2 = nm2;
    }
    const int myflag = (a2 - a1 < TAU) ? 1 : 0;

    float rpre[8];
#pragma unroll
    for (int g = 0; g < 8; ++g) rpre[g] = resid[((size_t)(row0 + g) << 6) + c];

    double com = 0.0, dnSum = 0.0;
#pragma unroll
    for (int g = 0; g < 8; ++g) {
      const int code_g = __shfl(ai, g << 3);
      const int flag_g = __shfl(myflag, g << 3);
      if (!flag_g) {                       // wave-uniform branch
        float q = cb[((size_t)code_g << 6) + c];
        float r = rpre[g] - q;
        resid[((size_t)(row0 + g) << 6) + c] = r;
        float p = r * r;
#pragma unroll
        for (int o = 32; o; o >>= 1) p += __shfl_down(p, o);
        if (c == 0) {
          codesF[(size_t)(row0 + g) * 8 + dep] = (float)code_g;
          com += (double)p;
        }
      }
      if (NEED_DN) {
        const double rc = (double)rpre[g];
        double mr = 0.0;
#pragma unroll 4
        for (int i = 0; i < 64; ++i)
          mr = fma(Mmat[i * 64 + c], (double)__shfl(rpre[g], i), mr);
        double qm = mr * rc;
        double av = rc * S1v[c];
        double b2 = rc * S2v[c];
        double r2 = rc * rc;
#pragma unroll
        for (int o = 32; o; o >>= 1) {
          qm += __shfl_down(qm, o);
          av += __shfl_down(av, o);
          b2 += __shfl_down(b2, o);
          r2 += __shfl_down(r2, o);
        }
        if (c == 0)
          dnSum += 8192.0 * r2 * r2 + CS[1] + 4.0 * qm
                 + 2.0 * r2 * CS[0] - 4.0 * r2 * av - 4.0 * b2;
      }
    }
    if (c == 0) { w4[team] = com; d4[team] = dnSum; }
    __syncthreads();
    if (t == 0) Pcom[b] = (w4[0] + w4[1]) + (w4[2] + w4[3]);
    if (NEED_DN && t == 1) Pdn[b] = (d4[0] + d4[1]) + (d4[2] + d4[3]);
  } else {
    // ---------------- refine path: 128 blocks x 256 rows ----------------
    __shared__ int list[256];
    __shared__ int wcnt[4];
    __shared__ int lcnt;
    __shared__ float rowv[64];
    __shared__ double vals[256];
    __shared__ int idxs[256];
    __shared__ int sbest;
    const int rb = blockIdx.x - 1024;
    const int row = rb * 256 + t;

    // per-thread merge of 8 slices (coalesced 32B/thread)
    const float* p1 = pm1 + row * 8;
    const float* p2 = pm2 + row * 8;
    const int* pv = pi1 + row * 8;
    float m1 = p1[0], m2 = p2[0];
    int ii = pv[0];
#pragma unroll
    for (int k = 1; k < 8; ++k) {
      float b1 = p1[k], b2 = p2[k];
      int bi = pv[k];
      m2 = fminf(fmaxf(m1, b1), fminf(m2, b2));
      if (b1 < m1) { m1 = b1; ii = bi; }
    }
    const bool flagged = (m2 - m1 < TAU);

    // deterministic (row-ordered) block-local flag list via ballot
    unsigned long long mask = __ballot(flagged);
    const int lane = t & 63;
    const int wid = t >> 6;
    if (lane == 0) wcnt[wid] = __popcll(mask);
    __syncthreads();
    int base = 0;
    for (int w = 0; w < wid; ++w) base += wcnt[w];
    if (flagged) list[base + __popcll(mask & ((1ull << lane) - 1ull))] = row;
    if (t == 0) lcnt = wcnt[0] + wcnt[1] + wcnt[2] + wcnt[3];
    __syncthreads();
    const int cnt = lcnt;

    double com = 0.0;
    for (int j = 0; j < cnt; ++j) {
      const int frow = list[j];
      __syncthreads();
      if (t < 64) rowv[t] = resid[((size_t)frow << 6) + t];
      __syncthreads();
      double bv = 1e300;
      int bi = 0x7fffffff;
      for (int i = 0; i < 32; ++i) {
        int k = i * 256 + t;
        const float* cp = cb + ((size_t)k << 6);
        double a0 = 0.0, a1d = 0.0, a2d = 0.0, a3d = 0.0;
#pragma unroll
        for (int d = 0; d < 64; d += 4) {
          a0  = fma((double)rowv[d    ], (double)cp[d    ], a0);
          a1d = fma((double)rowv[d + 1], (double)cp[d + 1], a1d);
          a2d = fma((double)rowv[d + 2], (double)cp[d + 2], a2d);
          a3d = fma((double)rowv[d + 3], (double)cp[d + 3], a3d);
        }
        double s = csqD[k] - 2.0 * ((a0 + a1d) + (a2d + a3d));
        if (s < bv) { bv = s; bi = k; }    // k ascends per thread: strict < keeps first
      }
      vals[t] = bv;
      idxs[t] = bi;
      __syncthreads();
      if (t == 0) {
        double g = vals[0]; int gi = idxs[0];
        for (int u = 1; u < 256; ++u) {
          if (vals[u] < g || (vals[u] == g && idxs[u] < gi)) { g = vals[u]; gi = idxs[u]; }
        }
        sbest = gi;
        codesF[(size_t)frow * 8 + dep] = (float)gi;
      }
      __syncthreads();
      if (t < 64) {
        float q = cb[((size_t)sbest << 6) + t];
        float r = rowv[t] - q;
        resid[((size_t)frow << 6) + t] = r;
        float p = r * r;
#pragma unroll
        for (int o = 32; o; o >>= 1) p += __shfl_down(p, o);
        if (t == 0) com += (double)p;
      }
      __syncthreads();
    }
    if (t == 0) Pcom[1024 + rb] = com;     // unconditional: slot always written
  }
}

// ---------------- (N,64)->(B,C,H,W) straight-through write-out ----------------
__global__ __launch_bounds__(256) void srq_writeout(
    const float* __restrict__ x, const float* __restrict__ resid, float* __restrict__ out)
{
  __shared__ float tile[64][65];
  const int b   = blockIdx.x >> 4;
  const int hw0 = (blockIdx.x & 15) << 6;
  const int t = threadIdx.x;
#pragma unroll
  for (int i = 0; i < 16; ++i) {
    int e = i * 256 + t;
    int hw = e >> 6, c = e & 63;
    tile[hw][c] = resid[((size_t)(b * 1024 + hw0 + hw) << 6) + c];
  }
  __syncthreads();
#pragma unroll
  for (int i = 0; i < 16; ++i) {
    int e = i * 256 + t;
    int c = e >> 6, hw = e & 63;
    size_t o = (size_t)b * 65536 + (size_t)c * 1024 + hw0 + hw;
    out[o] = x[o] - tile[hw][c];   // x + sg(q - x), q = x_code - resid
  }
}

// ------- final reduction: 8x1152 commit partials + 2x1024 dn partials -------
__global__ __launch_bounds__(256) void srq_finalize(
    const double* __restrict__ Pcom, const double* __restrict__ Pdn,
    float* __restrict__ outs)
{
  __shared__ double red[256];
  const int t = threadIdx.x;
  double s = 0.0;
  for (int i = t; i < 9216; i += 256) s += Pcom[i];
  red[t] = s;
  __syncthreads();
  for (int o = 128; o; o >>= 1) { if (t < o) red[t] += red[t + o]; __syncthreads(); }
  const double commit = red[0];
  __syncthreads();
  s = 0.0;
  for (int i = t; i < 1024; i += 256) s += Pdn[i];
  red[t] = s;
  __syncthreads();
  for (int o = 128; o; o >>= 1) { if (t < o) red[t] += red[t + o]; __syncthreads(); }
  const double dn0 = red[0];
  __syncthreads();
  s = 0.0;
  for (int i = t; i < 1024; i += 256) s += Pdn[1024 + i];
  red[t] = s;
  __syncthreads();
  for (int o = 128; o; o >>= 1) { if (t < o) red[t] += red[t + o]; __syncthreads(); }
  if (t == 0) {
    outs[0] = (float)(commit / 16777216.0);  // commit: mean over 8*32768*64
    outs[1] = (float)(red[0] / 32768.0);     // vqkd_d_norm  (depth 7)
    outs[2] = (float)(dn0 / 32768.0);        // vqgan_d_norm (depth 0)
  }
}

extern "C" void kernel_launch(void* const* d_in, const int* in_sizes, int n_in,
                              void* d_out, int out_size, void* d_ws, size_t ws_size,
                              hipStream_t stream) {
  const float* x  = (const float*)d_in[0];
  const float* cb = (const float*)d_in[1];
  char* ws = (char*)d_ws;

  float*  resid = (float*)(ws + OFF_RES);
  _Float16* Bh  = (_Float16*)(ws + OFF_BH);
  _Float16* Bl  = (_Float16*)(ws + OFF_BL);
  double* csqD  = (double*)(ws + OFF_CSQD);
  float*  csqH  = (float*)(ws + OFF_CSQH);
  float*  pm1   = (float*)(ws + OFF_PM1);
  float*  pm2   = (float*)(ws + OFF_PM2);
  int*    pi1   = (int*)(ws + OFF_PI1);
  double* M0    = (double*)(ws + OFF_M0);
  double* M7    = (double*)(ws + OFF_M7);
  double* S1_0  = (double*)(ws + OFF_DNP);
  double* S2_0  = (double*)(ws + OFF_DNP + 512);
  double* S1_7  = (double*)(ws + OFF_DNP + 1024);
  double* S2_7  = (double*)(ws + OFF_DNP + 1536);
  double* CS0   = (double*)(ws + OFF_DNP + 2048);
  double* CS7   = (double*)(ws + OFF_DNP + 2064);
  double* Pcom  = (double*)(ws + OFF_PCOM);
  double* Pdn   = (double*)(ws + OFF_PDN);

  // dnpre scratch (used only before the depth loop): reuse pm1/pm2/pi1
  double* Pm  = (double*)(ws + OFF_PM1);   // 32*4096*8 = 1 MB
  double* Ps1 = (double*)(ws + OFF_PM2);   // 16 KB
  double* Ps2 = (double*)(ws + OFF_PI1);   // 16 KB

  float* out_vqgan = (float*)d_out;
  float* out_vqkd  = out_vqgan + 2097152;
  float* out_scal  = out_vqgan + 4194304;
  float* out_codes = out_vqgan + 4194307;

  srq_transpose_init<<<512, 256, 0, stream>>>(x, resid);
  srq_csq<<<256, 256, 0, stream>>>(cb, csqD, csqH);
  srq_dnpre_partial<<<32, 256, 0, stream>>>(cb, csqD, Pm, Ps1, Ps2);
  srq_dnpre_reduce<<<17, 256, 0, stream>>>(Pm, Ps1, Ps2, csqD, M0, S1_0, S2_0, CS0);
  srq_dnpre_partial<<<32, 256, 0, stream>>>(cb + (size_t)7 * 524288, csqD + 7 * 8192,
                                            Pm, Ps1, Ps2);
  srq_dnpre_reduce<<<17, 256, 0, stream>>>(Pm, Ps1, Ps2, csqD + 7 * 8192,
                                           M7, S1_7, S2_7, CS7);
  srq_bconv<<<512, 256, 0, stream>>>(cb, Bh, Bl);

  for (int dep = 0; dep < 8; ++dep) {
    const float* cbd = cb + (size_t)dep * 524288;
    const float* cbn = (dep < 7) ? cb + (size_t)(dep + 1) * 524288 : nullptr;
    srq_screen_mfma<<<2048, 256, 0, stream>>>(Bh, Bl, csqH + dep * 8192, resid, pm1, pm2, pi1);
    if (dep == 0 || dep == 7) {
      srq_post<1><<<1152, 256, 0, stream>>>(pm1, pm2, pi1, cbd, csqD + dep * 8192,
          resid, out_codes, Pcom + (size_t)dep * 1152, Pdn + (dep == 0 ? 0 : 1024),
          (dep == 0 ? M0 : M7), (dep == 0 ? S1_0 : S1_7),
          (dep == 0 ? S2_0 : S2_7), (dep == 0 ? CS0 : CS7),
          cbn, Bh, Bl, dep);
    } else {
      srq_post<0><<<1152, 256, 0, stream>>>(pm1, pm2, pi1, cbd, csqD + dep * 8192,
          resid, out_codes, Pcom + (size_t)dep * 1152, nullptr,
          nullptr, nullptr, nullptr, nullptr,
          cbn, Bh, Bl, dep);
    }
    if (dep == 0) srq_writeout<<<512, 256, 0, stream>>>(x, resid, out_vqgan);
    if (dep == 7) srq_writeout<<<512, 256, 0, stream>>>(x, resid, out_vqkd);
  }
  srq_finalize<<<1, 256, 0, stream>>>(Pcom, Pdn, out_scal);
}

// Round 15
// 1854.223 us; speedup vs baseline: 1.2893x; 1.2893x over previous
//
#include <hip/hip_runtime.h>

// SharedResidualQuantizer: 8-step residual VQ, N=32768 rows, K=8192 codes, d=64.
// Screen: f16 hi/scaled-lo MFMA, LDS-staged, 32 rows/wave, (256,3) — DO NOT raise
//   to (256,4): unified-RF allocator splits arch-VGPR to 64 and spills (r8,r10).
// Post-screen path (r13, measured best): merge_row (1 thread/row) -> refine
//   (codes-only) -> update (streaming, loads-up-front, 1 barrier, per-block
//   partials, fused bconv). DO NOT fuse these (r11/r12/r14: all fusions lose —
//   branch-guarded gathers kill MLP; thin parallel kernels win).
//
// ws layout (bytes):
#define OFF_RES    0u          // resid f32 N*64                     (8 MB)
#define OFF_BH     8388608u    // Bh f16 8192*64 (per-depth)         (1 MB)
#define OFF_BL     9437184u    // Bl f16 (scaled 2^11)               (1 MB)
#define OFF_CSQD   10485760u   // csqD f64 8*8192                    (512 KB)
#define OFF_CSQH   11010048u   // csqH f32 8*8192 = -csq/2           (256 KB)
#define OFF_CODES  11272192u   // codes i32 N                        (128 KB)
#define OFF_PM1    11403264u   // per-slice partials, N*8 each       (1 MB each)
#define OFF_PM2    12451840u   //   (pm1/pm2/pi1 double as dnpre scratch at startup)
#define OFF_PI1    13500416u
#define OFF_FLAG   14548992u   // flag list i32 N                    (128 KB)
#define OFF_M0     14680064u   // M fp64 64x64, depth 0              (32 KB)
#define OFF_M7     14712832u   // M fp64 64x64, depth 7              (32 KB)
#define OFF_DNP    14745600u   // S1_0,S2_0,S1_7,S2_7 (512B each) + CS0,CS7 (16B each)
#define OFF_FCNT   14749696u   // 8 i32 flag counters (zeroed once)
#define OFF_PCOM   14749760u   // per-block commit partials f64 8*1024 (64 KB)
#define OFF_PDN    15274048u   // per-block dn partials f64 2*1024   (16 KB)

#define TAU 3.0e-3f

typedef __attribute__((ext_vector_type(8))) _Float16 f16x8;
typedef __attribute__((ext_vector_type(4))) float f32x4;

__device__ __forceinline__ f32x4 mfma16(f16x8 a, f16x8 b, f32x4 c) {
  return __builtin_amdgcn_mfma_f32_16x16x32_f16(a, b, c, 0, 0, 0);
}

// ---------------- transpose x (B,C,H,W)->(N,64) into resid ----------------
__global__ __launch_bounds__(256) void srq_transpose_init(
    const float* __restrict__ x, float* __restrict__ resid)
{
  __shared__ float tile[64][65];
  const int b   = blockIdx.x >> 4;
  const int hw0 = (blockIdx.x & 15) << 6;
  const int t = threadIdx.x;
#pragma unroll
  for (int i = 0; i < 16; ++i) {
    int e = i * 256 + t;
    int c = e >> 6, hw = e & 63;
    tile[c][hw] = x[(size_t)b * 65536 + (size_t)c * 1024 + hw0 + hw];
  }
  __syncthreads();
#pragma unroll
  for (int i = 0; i < 16; ++i) {
    int e = i * 256 + t;
    int hw = e >> 6, c = e & 63;
    resid[((size_t)(b * 1024 + hw0 + hw) << 6) + c] = tile[c][hw];
  }
}

// ---------------- ||c||^2 (fp64) and -||c||^2/2 (f32) for all (depth,k) ----------------
__global__ __launch_bounds__(256) void srq_csq(
    const float* __restrict__ cb, double* __restrict__ csqD, float* __restrict__ csqH)
{
  int id = blockIdx.x * 256 + threadIdx.x;   // 65536
  const float* p = cb + ((size_t)id << 6);
  double s = 0.0;
#pragma unroll 8
  for (int d = 0; d < 64; ++d) { double v = (double)p[d]; s = fma(v, v, s); }
  csqD[id] = s;
  csqH[id] = (float)(-0.5 * s);
}

// ---------------- codebook -> f16 hi + scaled lo (depth 0 bootstrap) ----------------
__global__ __launch_bounds__(256) void srq_bconv(
    const float* __restrict__ cb, _Float16* __restrict__ Bh, _Float16* __restrict__ Bl)
{
  int id0 = (blockIdx.x * 256 + threadIdx.x) * 4;   // 512 blocks x 4/thread = 524288
  float4 v = *(const float4*)(cb + id0);
  const float f[4] = {v.x, v.y, v.z, v.w};
#pragma unroll
  for (int u = 0; u < 4; ++u) {
    _Float16 h = (_Float16)f[u];
    Bh[id0 + u] = h;
    Bl[id0 + u] = (_Float16)((f[u] - (float)h) * 2048.f);
  }
}

// ---- d_norm precompute stage 1: per-block fp64 partials of M=sum c c^T,
// ---- S1=sum c, S2=sum csq*c.  32 blocks x 256 k each. Deterministic. ----
__global__ __launch_bounds__(256) void srq_dnpre_partial(
    const float* __restrict__ cb, const double* __restrict__ csqD,
    double* __restrict__ Pm, double* __restrict__ Ps1, double* __restrict__ Ps2)
{
  __shared__ float ch[32][64];
  const int t = threadIdx.x;
  const int b = blockIdx.x;
  const int i = t >> 2;              // M row (constant per thread)
  const int j0 = (t & 3) << 4;       // M col base (16 cols per thread)
  double acc[16];
#pragma unroll
  for (int n = 0; n < 16; ++n) acc[n] = 0.0;
  double s1 = 0.0, s2 = 0.0;
  for (int c8 = 0; c8 < 8; ++c8) {
    const int kbase = b * 256 + c8 * 32;
    __syncthreads();
    const float* src = cb + (size_t)kbase * 64;
#pragma unroll
    for (int u = 0; u < 2; ++u)
      *(float4*)(&ch[0][0] + (u * 256 + t) * 4) = *(const float4*)(src + (u * 256 + t) * 4);
    __syncthreads();
#pragma unroll 4
    for (int kk = 0; kk < 32; ++kk) {
      double ci = (double)ch[kk][i];
#pragma unroll
      for (int n = 0; n < 16; ++n)
        acc[n] = fma(ci, (double)ch[kk][j0 + n], acc[n]);
    }
    if (t < 64) {
#pragma unroll 4
      for (int kk = 0; kk < 32; ++kk) {
        double v = (double)ch[kk][t];
        s1 += v;
        s2 = fma(csqD[kbase + kk], v, s2);
      }
    }
  }
  double* dst = Pm + ((size_t)b << 12) + (i << 6) + j0;
#pragma unroll
  for (int n = 0; n < 16; ++n) dst[n] = acc[n];
  if (t < 64) { Ps1[(b << 6) + t] = s1; Ps2[(b << 6) + t] = s2; }
}

// ---- d_norm precompute stage 2: reduce partials (fixed order) + CS ----
__global__ __launch_bounds__(256) void srq_dnpre_reduce(
    const double* __restrict__ Pm, const double* __restrict__ Ps1,
    const double* __restrict__ Ps2, const double* __restrict__ csqD,
    double* __restrict__ Mmat, double* __restrict__ S1, double* __restrict__ S2,
    double* __restrict__ CS)
{
  const int t = threadIdx.x;
  if (blockIdx.x < 16) {
    const int e = blockIdx.x * 256 + t;
    double a = 0.0;
    for (int b = 0; b < 32; ++b) a += Pm[((size_t)b << 12) + e];
    Mmat[e] = a;
  } else {
    __shared__ double red[256];
    if (t < 64) {
      double a1 = 0.0, a2 = 0.0;
      for (int b = 0; b < 32; ++b) { a1 += Ps1[(b << 6) + t]; a2 += Ps2[(b << 6) + t]; }
      S1[t] = a1; S2[t] = a2;
    }
    double c1 = 0.0, c2 = 0.0;
    for (int k = t; k < 8192; k += 256) { double q = csqD[k]; c1 += q; c2 = fma(q, q, c2); }
    red[t] = c1;
    __syncthreads();
    for (int o = 128; o; o >>= 1) { if (t < o) red[t] += red[t + o]; __syncthreads(); }
    if (t == 0) CS[0] = red[0];
    __syncthreads();
    red[t] = c2;
    __syncthreads();
    for (int o = 128; o; o >>= 1) { if (t < o) red[t] += red[t + o]; __syncthreads(); }
    if (t == 0) CS[1] = red[0];
  }
}

// ---------------- stage one 64-code tile (hi+lo, 16 KB) to LDS ----------------
__device__ __forceinline__ void stage_tile(
    const _Float16* __restrict__ Bh, const _Float16* __restrict__ Bl,
    char* ldsbase, int k0, int wid, int lane)
{
#pragma unroll
  for (int q = 0; q < 4; ++q) {
    int ub = (((q << 2) + wid) << 10);       // wave-uniform dest base (1 KB chunks)
    int db = ub + lane * 16;                 // effective dest byte (for src swizzle)
    int half = db >> 13;                     // 0 = hi tile, 1 = lo tile
    int rowh = (db & 8191) >> 7;             // code row within half
    int soff = (db & 127) ^ ((rowh & 7) << 4);  // inverse-swizzled source offset
    const _Float16* g = (half ? Bl : Bh) + (((size_t)(k0 + rowh)) << 6) + (soff >> 1);
    __builtin_amdgcn_global_load_lds(
        (const __attribute__((address_space(1))) void*)g,
        (__attribute__((address_space(3))) void*)(ldsbase + ub), 16, 0, 0);
  }
}

// ------- MFMA screen: 32 rows/wave, LDS-staged B, per-row top-2 over 1024 codes -------
// (256,3): compiler-chosen 84 VGPR, no split/spill. Measured: (256,4) spills (r8,r10).
__global__ __launch_bounds__(256, 3) void srq_screen_mfma(
    const _Float16* __restrict__ Bh, const _Float16* __restrict__ Bl,
    const float* __restrict__ csqH, const float* __restrict__ resid,
    float* __restrict__ pm1, float* __restrict__ pm2, int* __restrict__ pi1)
{
  __shared__ char lds[32768];                // 2 bufs x (Bh 8KB + Bl 8KB)
  const int tid = threadIdx.x;
  const int lane = tid & 63;
  const int wid = tid >> 6;
  const int rg = blockIdx.x & 255;           // row group (128 rows/block)
  const int ks = blockIdx.x >> 8;            // k slice (1024 codes)
  const int k0g = ks << 10;
  const int wrow0 = (rg << 7) + (wid << 5);  // wave owns 32 rows
  const int lr = lane & 15;
  const int kg = lane >> 4;

  // A fragments: 32 rows x 64 d, f16 hi + scaled lo, from exact f32 residual
  f16x8 ah[2][2], al[2][2];
#pragma unroll
  for (int rf = 0; rf < 2; ++rf)
#pragma unroll
    for (int s = 0; s < 2; ++s) {
      const float* rp = resid + (((size_t)(wrow0 + rf * 16 + lr)) << 6) + s * 32 + kg * 8;
      float4 v0 = *(const float4*)rp;
      float4 v1 = *(const float4*)(rp + 4);
      float f[8] = {v0.x, v0.y, v0.z, v0.w, v1.x, v1.y, v1.z, v1.w};
      f16x8 h, l;
#pragma unroll
      for (int e = 0; e < 8; ++e) {
        _Float16 hh = (_Float16)f[e];
        h[e] = hh;
        l[e] = (_Float16)((f[e] - (float)hh) * 2048.f);
      }
      ah[rf][s] = h;
      al[rf][s] = l;
    }

  // top-2 tracked in sigma-domain (sigma = -s/2; argmin s == argmax sigma)
  float m1[8], m2[8];
  int i1[8];
#pragma unroll
  for (int j = 0; j < 8; ++j) { m1[j] = -3e38f; m2[j] = -3e38f; i1[j] = 0; }

  stage_tile(Bh, Bl, lds, k0g, wid, lane);

  for (int t = 0; t < 16; ++t) {
    __syncthreads();   // compiler drains vmcnt here: staged tile t visible
    if (t < 15) stage_tile(Bh, Bl, lds + (((t + 1) & 1) << 14), k0g + ((t + 1) << 6), wid, lane);
    const char* bb = lds + ((t & 1) << 14);
    const int k0 = k0g + (t << 6);
#pragma unroll
    for (int cf = 0; cf < 4; ++cf) {
      const int cl = cf * 16 + lr;           // local code (B-frag col)
      const int sw = (cl & 7) << 4;          // XOR swizzle
      const int ro = cl * 128 + kg * 16;
      f16x8 bh0 = *(const f16x8*)(bb + ((ro) ^ sw));
      f16x8 bh1 = *(const f16x8*)(bb + ((ro + 64) ^ sw));
      f16x8 bl0 = *(const f16x8*)(bb + 8192 + ((ro) ^ sw));
      f16x8 bl1 = *(const f16x8*)(bb + 8192 + ((ro + 64) ^ sw));
      const int code = k0 + cl;
      const float ci = csqH[code];           // -csq/2, folded into acc init
#pragma unroll
      for (int rf = 0; rf < 2; ++rf) {
        f32x4 a1 = {ci, ci, ci, ci};         // hi*hi (exact products) - csq/2
        f32x4 a2 = {0.f, 0.f, 0.f, 0.f};     // cross terms at 2^11 scale
        a1 = mfma16(ah[rf][0], bh0, a1);
        a1 = mfma16(ah[rf][1], bh1, a1);
        a2 = mfma16(ah[rf][0], bl0, a2);
        a2 = mfma16(al[rf][0], bh0, a2);
        a2 = mfma16(ah[rf][1], bl1, a2);
        a2 = mfma16(al[rf][1], bh1, a2);
#pragma unroll
        for (int r = 0; r < 4; ++r) {
          // sigma = -s/2 = a1 + 2^-11*a2 ; bigger sigma == smaller dist
          float sg = fmaf(4.8828125e-4f, a2[r], a1[r]);
          const int j = rf * 4 + r;          // row = wrow0 + rf*16 + kg*4 + r
          bool gt = sg > m1[j];
          m2[j] = __builtin_amdgcn_fmed3f(sg, m1[j], m2[j]);
          m1[j] = fmaxf(m1[j], sg);
          i1[j] = gt ? code : i1[j];
        }
      }
    }
  }

  // merge across the 16 lanes (lane^{1,2,4,8}) sharing each row; max-domain
#pragma unroll
  for (int j = 0; j < 8; ++j) {
    float a1 = m1[j], a2 = m2[j];
    int ai = i1[j];
#pragma unroll
    for (int w = 1; w <= 8; w <<= 1) {
      float b1 = __shfl_xor(a1, w);
      float b2 = __shfl_xor(a2, w);
      int bi = __shfl_xor(ai, w);
      float nm2 = fmaxf(fminf(a1, b1), fmaxf(a2, b2));
      bool bet = (b1 > a1) || (b1 == a1 && bi < ai);
      a1 = fmaxf(a1, b1);
      ai = bet ? bi : ai;
      a2 = nm2;
    }
    if (lr == 0) {
      const int row = wrow0 + (j >> 2) * 16 + kg * 4 + (j & 3);
      pm1[row * 8 + ks] = -2.f * a1;         // back to s-domain
      pm2[row * 8 + ks] = -2.f * a2;
      pi1[row * 8 + ks] = ai;
    }
  }
}

// ------- merge 8 slices, ONE THREAD PER ROW (coalesced), flag ambiguous -------
__global__ __launch_bounds__(256) void srq_merge_row(
    const float* __restrict__ pm1, const float* __restrict__ pm2,
    const int* __restrict__ pi1, int* __restrict__ codes,
    int* __restrict__ flagList, int* __restrict__ flagCnt)
{
  const int row = blockIdx.x * 256 + threadIdx.x;   // 128 blocks
  const float* p1 = pm1 + row * 8;
  const float* p2 = pm2 + row * 8;
  const int*   pv = pi1 + row * 8;
  float m1 = p1[0], m2 = p2[0];
  int ii = pv[0];
#pragma unroll
  for (int k = 1; k < 8; ++k) {
    float b1 = p1[k], b2 = p2[k];
    int bi = pv[k];
    m2 = fminf(fmaxf(m1, b1), fminf(m2, b2));
    if (b1 < m1) { m1 = b1; ii = bi; }       // slices ascend: ties keep earlier
  }
  codes[row] = ii;
  if (m2 - m1 < TAU) {
    int pos = atomicAdd(flagCnt, 1);
    flagList[pos] = row;
  }
}

// ------- fp64 exact re-scoring of flagged rows (codes only; update runs after) -------
__global__ __launch_bounds__(256) void srq_refine(
    const float* __restrict__ cb, const double* __restrict__ csqD,
    const float* __restrict__ resid, int* __restrict__ codes,
    const int* __restrict__ flagList, const int* __restrict__ flagCnt)
{
  __shared__ float rowv[64];
  __shared__ double vals[256];
  __shared__ int   idxs[256];
  int cnt = *flagCnt;
  for (int j = blockIdx.x; j < cnt; j += gridDim.x) {
    int row = flagList[j];
    __syncthreads();
    if (threadIdx.x < 64) rowv[threadIdx.x] = resid[((size_t)row << 6) + threadIdx.x];
    __syncthreads();
    double bv = 1e300;
    int bi = 0x7fffffff;
    for (int i = 0; i < 32; ++i) {
      int k = i * 256 + threadIdx.x;
      const float* cp = cb + ((size_t)k << 6);
      double a0 = 0.0, a1 = 0.0, a2 = 0.0, a3 = 0.0;
#pragma unroll
      for (int d = 0; d < 64; d += 4) {
        a0 = fma((double)rowv[d    ], (double)cp[d    ], a0);
        a1 = fma((double)rowv[d + 1], (double)cp[d + 1], a1);
        a2 = fma((double)rowv[d + 2], (double)cp[d + 2], a2);
        a3 = fma((double)rowv[d + 3], (double)cp[d + 3], a3);
      }
      double s = csqD[k] - 2.0 * ((a0 + a1) + (a2 + a3));
      if (s < bv) { bv = s; bi = k; }        // k ascends per thread: strict < keeps first
    }
    vals[threadIdx.x] = bv;
    idxs[threadIdx.x] = bi;
    __syncthreads();
    if (threadIdx.x == 0) {
      double g = vals[0]; int gi = idxs[0];
      for (int u = 1; u < 256; ++u) {
        if (vals[u] < g || (vals[u] == g && idxs[u] < gi)) { g = vals[u]; gi = idxs[u]; }
      }
      codes[row] = gi;
    }
    __syncthreads();
  }
}

// ------- streaming update: resid/commit/codesF + algebraic dn + fused bconv -------
// 1024 blocks x 32 rows. All loads issued up front (high MLP), ONE barrier.
// Per-block partials Pcom/Pdn: fully deterministic commit.
template <int NEED_DN>
__global__ __launch_bounds__(256) void srq_update(
    const float* __restrict__ cb, float* __restrict__ resid,
    const int* __restrict__ codes, float* __restrict__ codesF,
    double* __restrict__ Pcom, double* __restrict__ Pdn,
    const double* __restrict__ Mmat, const double* __restrict__ S1v,
    const double* __restrict__ S2v, const double* __restrict__ CS,
    const float* __restrict__ cbNext, _Float16* __restrict__ BhN,
    _Float16* __restrict__ BlN, int dep)
{
  __shared__ double w4[4];
  __shared__ double d4[4];
  const int t = threadIdx.x;
  const int team = t >> 6;
  const int c = t & 63;

  // fused bconv for next depth: 1024 blocks x 256 threads x 2 = 524288 elems
  if (cbNext) {
    int gid = blockIdx.x * 512 + t;
#pragma unroll
    for (int u = 0; u < 2; ++u) {
      int g2 = gid + u * 256;
      float v = cbNext[g2];
      _Float16 h = (_Float16)v;
      BhN[g2] = h;
      BlN[g2] = (_Float16)((v - (float)h) * 2048.f);
    }
  }

  int rows[8], cds[8];
#pragma unroll
  for (int g = 0; g < 8; ++g) {
    rows[g] = (blockIdx.x * 8 + g) * 4 + team;
    cds[g] = codes[rows[g]];
  }
  float rpre[8], qv[8];
#pragma unroll
  for (int g = 0; g < 8; ++g) rpre[g] = resid[((size_t)rows[g] << 6) + c];
#pragma unroll
  for (int g = 0; g < 8; ++g) qv[g] = cb[((size_t)cds[g] << 6) + c];

  double com = 0.0, dnSum = 0.0;
#pragma unroll
  for (int g = 0; g < 8; ++g) {
    float r = rpre[g] - qv[g];
    resid[((size_t)rows[g] << 6) + c] = r;
    float p = r * r;
#pragma unroll
    for (int o = 32; o; o >>= 1) p += __shfl_down(p, o);
    if (c == 0) {
      codesF[(size_t)rows[g] * 8 + dep] = (float)cds[g];
      com += (double)p;
    }
  }

  if (NEED_DN) {
#pragma unroll 1
    for (int g = 0; g < 8; ++g) {
      const double rc = (double)rpre[g];
      double mr = 0.0;
#pragma unroll 4
      for (int i = 0; i < 64; ++i)
        mr = fma(Mmat[i * 64 + c], (double)__shfl(rpre[g], i), mr);
      double qm = mr * rc;          // -> r^T M r
      double av = rc * S1v[c];      // -> r . S1
      double b2 = rc * S2v[c];      // -> r . S2
      double r2 = rc * rc;          // -> rsq (fp64)
#pragma unroll
      for (int o = 32; o; o >>= 1) {
        qm += __shfl_down(qm, o);
        av += __shfl_down(av, o);
        b2 += __shfl_down(b2, o);
        r2 += __shfl_down(r2, o);
      }
      if (c == 0)
        dnSum += 8192.0 * r2 * r2 + CS[1] + 4.0 * qm
               + 2.0 * r2 * CS[0] - 4.0 * r2 * av - 4.0 * b2;
    }
  }

  if (c == 0) { w4[team] = com; d4[team] = dnSum; }
  __syncthreads();
  if (t == 0) Pcom[blockIdx.x] = (w4[0] + w4[1]) + (w4[2] + w4[3]);
  if (NEED_DN && t == 1) Pdn[blockIdx.x] = (d4[0] + d4[1]) + (d4[2] + d4[3]);
}

// ---------------- (N,64)->(B,C,H,W) straight-through write-out ----------------
__global__ __launch_bounds__(256) void srq_writeout(
    const float* __restrict__ x, const float* __restrict__ resid, float* __restrict__ out)
{
  __shared__ float tile[64][65];
  const int b   = blockIdx.x >> 4;
  const int hw0 = (blockIdx.x & 15) << 6;
  const int t = threadIdx.x;
#pragma unroll
  for (int i = 0; i < 16; ++i) {
    int e = i * 256 + t;
    int hw = e >> 6, c = e & 63;
    tile[hw][c] = resid[((size_t)(b * 1024 + hw0 + hw) << 6) + c];
  }
  __syncthreads();
#pragma unroll
  for (int i = 0; i < 16; ++i) {
    int e = i * 256 + t;
    int c = e >> 6, hw = e & 63;
    size_t o = (size_t)b * 65536 + (size_t)c * 1024 + hw0 + hw;
    out[o] = x[o] - tile[hw][c];   // x + sg(q - x), q = x_code - resid
  }
}

// ------- final reduction: 8x1024 commit partials + 2x1024 dn partials -------
__global__ __launch_bounds__(256) void srq_finalize(
    const double* __restrict__ Pcom, const double* __restrict__ Pdn,
    float* __restrict__ outs)
{
  __shared__ double red[256];
  const int t = threadIdx.x;
  double s = 0.0;
  for (int i = t; i < 8192; i += 256) s += Pcom[i];
  red[t] = s;
  __syncthreads();
  for (int o = 128; o; o >>= 1) { if (t < o) red[t] += red[t + o]; __syncthreads(); }
  const double commit = red[0];
  __syncthreads();
  s = 0.0;
  for (int i = t; i < 1024; i += 256) s += Pdn[i];
  red[t] = s;
  __syncthreads();
  for (int o = 128; o; o >>= 1) { if (t < o) red[t] += red[t + o]; __syncthreads(); }
  const double dn0 = red[0];
  __syncthreads();
  s = 0.0;
  for (int i = t; i < 1024; i += 256) s += Pdn[1024 + i];
  red[t] = s;
  __syncthreads();
  for (int o = 128; o; o >>= 1) { if (t < o) red[t] += red[t + o]; __syncthreads(); }
  if (t == 0) {
    outs[0] = (float)(commit / 16777216.0);  // commit: mean over 8*32768*64
    outs[1] = (float)(red[0] / 32768.0);     // vqkd_d_norm  (depth 7)
    outs[2] = (float)(dn0 / 32768.0);        // vqgan_d_norm (depth 0)
  }
}

extern "C" void kernel_launch(void* const* d_in, const int* in_sizes, int n_in,
                              void* d_out, int out_size, void* d_ws, size_t ws_size,
                              hipStream_t stream) {
  const float* x  = (const float*)d_in[0];
  const float* cb = (const float*)d_in[1];
  char* ws = (char*)d_ws;

  float*  resid = (float*)(ws + OFF_RES);
  _Float16* Bh  = (_Float16*)(ws + OFF_BH);
  _Float16* Bl  = (_Float16*)(ws + OFF_BL);
  double* csqD  = (double*)(ws + OFF_CSQD);
  float*  csqH  = (float*)(ws + OFF_CSQH);
  int*    codes = (int*)(ws + OFF_CODES);
  float*  pm1   = (float*)(ws + OFF_PM1);
  float*  pm2   = (float*)(ws + OFF_PM2);
  int*    pi1   = (int*)(ws + OFF_PI1);
  int*    flags = (int*)(ws + OFF_FLAG);
  double* M0    = (double*)(ws + OFF_M0);
  double* M7    = (double*)(ws + OFF_M7);
  double* S1_0  = (double*)(ws + OFF_DNP);
  double* S2_0  = (double*)(ws + OFF_DNP + 512);
  double* S1_7  = (double*)(ws + OFF_DNP + 1024);
  double* S2_7  = (double*)(ws + OFF_DNP + 1536);
  double* CS0   = (double*)(ws + OFF_DNP + 2048);
  double* CS7   = (double*)(ws + OFF_DNP + 2064);
  int*    fcnt  = (int*)(ws + OFF_FCNT);
  double* Pcom  = (double*)(ws + OFF_PCOM);
  double* Pdn   = (double*)(ws + OFF_PDN);

  // dnpre scratch (used only before the depth loop): reuse pm1/pm2/pi1
  double* Pm  = (double*)(ws + OFF_PM1);   // 32*4096*8 = 1 MB
  double* Ps1 = (double*)(ws + OFF_PM2);   // 16 KB
  double* Ps2 = (double*)(ws + OFF_PI1);   // 16 KB

  float* out_vqgan = (float*)d_out;
  float* out_vqkd  = out_vqgan + 2097152;
  float* out_scal  = out_vqgan + 4194304;
  float* out_codes = out_vqgan + 4194307;

  hipMemsetAsync(ws + OFF_FCNT, 0, 32, stream);
  srq_transpose_init<<<512, 256, 0, stream>>>(x, resid);
  srq_csq<<<256, 256, 0, stream>>>(cb, csqD, csqH);
  srq_dnpre_partial<<<32, 256, 0, stream>>>(cb, csqD, Pm, Ps1, Ps2);
  srq_dnpre_reduce<<<17, 256, 0, stream>>>(Pm, Ps1, Ps2, csqD, M0, S1_0, S2_0, CS0);
  srq_dnpre_partial<<<32, 256, 0, stream>>>(cb + (size_t)7 * 524288, csqD + 7 * 8192,
                                            Pm, Ps1, Ps2);
  srq_dnpre_reduce<<<17, 256, 0, stream>>>(Pm, Ps1, Ps2, csqD + 7 * 8192,
                                           M7, S1_7, S2_7, CS7);
  srq_bconv<<<512, 256, 0, stream>>>(cb, Bh, Bl);

  for (int dep = 0; dep < 8; ++dep) {
    const float* cbd = cb + (size_t)dep * 524288;
    const float* cbn = (dep < 7) ? cb + (size_t)(dep + 1) * 524288 : nullptr;
    srq_screen_mfma<<<2048, 256, 0, stream>>>(Bh, Bl, csqH + dep * 8192, resid, pm1, pm2, pi1);
    srq_merge_row<<<128, 256, 0, stream>>>(pm1, pm2, pi1, codes, flags, fcnt + dep);
    srq_refine<<<128, 256, 0, stream>>>(cbd, csqD + dep * 8192, resid, codes,
                                        flags, fcnt + dep);
    if (dep == 0 || dep == 7) {
      srq_update<1><<<1024, 256, 0, stream>>>(cbd, resid, codes, out_codes,
          Pcom + (size_t)dep * 1024, Pdn + (dep == 0 ? 0 : 1024),
          (dep == 0 ? M0 : M7), (dep == 0 ? S1_0 : S1_7),
          (dep == 0 ? S2_0 : S2_7), (dep == 0 ? CS0 : CS7),
          cbn, Bh, Bl, dep);
    } else {
      srq_update<0><<<1024, 256, 0, stream>>>(cbd, resid, codes, out_codes,
          Pcom + (size_t)dep * 1024, nullptr,
          nullptr, nullptr, nullptr, nullptr,
          cbn, Bh, Bl, dep);
    }
    if (dep == 0) srq_writeout<<<512, 256, 0, stream>>>(x, resid, out_vqgan);
    if (dep == 7) srq_writeout<<<512, 256, 0, stream>>>(x, resid, out_vqkd);
  }
  srq_finalize<<<1, 256, 0, stream>>>(Pcom, Pdn, out_scal);
}